// Round 6
// baseline (145.459 us; speedup 1.0000x reference)
//
#include <hip/hip_runtime.h>
#include <math.h>

#define H 768
#define L 256
#define NB 4
#define NL 13

typedef _Float16 h2 __attribute__((ext_vector_type(2)));
typedef _Float16 half8 __attribute__((ext_vector_type(8)));
typedef float f32x4 __attribute__((ext_vector_type(4)));

// Packed-fp16 GELU: erf(x/sqrt2) ~= xc*P(v), v = (xc*xc)/8, xc = clamp(x,+-3.75).
// Coefficients rescaled so all are fp16-normal. ~11 v_pk ops per 2 elements.
__device__ inline h2 gelu_pk(h2 x) {
    const _Float16 kC = (_Float16)3.75f;
    h2 hi = {kC, kC}, lo = {(_Float16)-3.75f, (_Float16)-3.75f};
    h2 xc = __builtin_elementwise_min(__builtin_elementwise_max(x, lo), hi);
    h2 u = xc * xc;
    const _Float16 kE = (_Float16)0.125f;
    h2 ve = {kE, kE};
    h2 v = u * ve;
    const _Float16 d4v = (_Float16)0.0832840f,  d3v = (_Float16)-0.4335206f;
    const _Float16 d2v = (_Float16)0.8960128f,  d1v = (_Float16)-0.9876456f;
    const _Float16 d0v = (_Float16)0.7946463f;
    h2 d4 = {d4v, d4v}, d3 = {d3v, d3v}, d2 = {d2v, d2v}, d1 = {d1v, d1v}, d0 = {d0v, d0v};
    h2 p = v * (v * (v * (v * d4 + d3) + d2) + d1) + d0;   // -> v_pk_fma_f16 chain
    h2 t = xc * p;
    const _Float16 kH = (_Float16)0.5f;
    h2 halfv = {kH, kH};
    h2 hx = x * halfv;
    return hx * t + hx;
}

// ---------------- Kernel 1: fused prep + GEMM --------------------------------
// grid (48, 9). by<8: block computes C[m0..m0+128][n0g..n0g+32], K=768.
//   W1 n'-strip (768x32) staged TRANSPOSED in LDS as fp16 [n][k] (pitch 776,
//   rows 16B-aligned) -> B-frags are single ds_read_b128. A-frags read fp32 X
//   directly (row-major == A-frag order), cvt to fp16 in-register.
//   n'<768 -> Pxs2 fp16 (+b1); n'>=768 -> Pxe fp16.
// by==8, bx==0: build W2 B-fragments (Bfrag2[kb][lane][8], n=ln<13 else 0).
__global__ __launch_bounds__(256) void fused_gemm(
    const float* __restrict__ X, const float* __restrict__ W1,
    const float* __restrict__ b1, const float* __restrict__ W2,
    _Float16* __restrict__ Pxs2, _Float16* __restrict__ Pxe,
    _Float16* __restrict__ Bfrag2)
{
    const int tid = threadIdx.x;

    if (blockIdx.y == 8) {
        if (blockIdx.x != 0) return;
        // 12288 frag elements, 48 per thread
        for (int r = 0; r < 48; ++r) {
            int idx = r * 256 + tid;
            int u = idx & 7;
            int lane = (idx >> 3) & 63;
            int kb = idx >> 9;
            int k = kb * 32 + ((lane >> 4) << 3) + u;
            int n = lane & 15;
            float v = (n < NL) ? W2[(size_t)k * NL + n] : 0.f;
            Bfrag2[idx] = (_Float16)v;
        }
        return;
    }

    __shared__ _Float16 Ts[32][776];             // [n][k], 49.7 KB, rows 16B-aligned
    const int wv = tid >> 6, lane = tid & 63;
    const int ln = lane & 15, quad = lane >> 4;
    const int n0g = blockIdx.x * 32;             // n' in [0,1536)
    const bool isE = (n0g >= H);
    const float* Wb = W1 + (isE ? (size_t)H * H : 0);
    const int c0 = isE ? (n0g - H) : n0g;
    const int m0 = blockIdx.y * 128 + wv * 32;

    // ---- stage W1 strip: 768 k-rows x 32 n (fp32) -> Ts[n][k] fp16 ----
    #pragma unroll
    for (int r = 0; r < 24; ++r) {
        int idx = r * 256 + tid;
        int k = idx >> 3;
        int c4 = (idx & 7) << 2;
        float4 f = *(const float4*)&Wb[(size_t)k * H + c0 + c4];
        Ts[c4 + 0][k] = (_Float16)f.x;
        Ts[c4 + 1][k] = (_Float16)f.y;
        Ts[c4 + 2][k] = (_Float16)f.z;
        Ts[c4 + 3][k] = (_Float16)f.w;
    }
    __syncthreads();

    const float* px0 = X + (size_t)(m0 + ln) * H + quad * 8;
    const float* px1 = px0 + (size_t)16 * H;

    f32x4 acc[2][2] = {};
    #pragma unroll 2
    for (int kb = 0; kb < H / 32; ++kb) {
        const int k8 = kb * 32 + quad * 8;
        // A-frags: 8 consecutive fp32 from X, convert
        half8 afr[2];
        {
            float4 xa = *(const float4*)(px0 + kb * 32);
            float4 xb = *(const float4*)(px0 + kb * 32 + 4);
            half8 a = { (_Float16)xa.x, (_Float16)xa.y, (_Float16)xa.z, (_Float16)xa.w,
                        (_Float16)xb.x, (_Float16)xb.y, (_Float16)xb.z, (_Float16)xb.w };
            afr[0] = a;
            float4 ya = *(const float4*)(px1 + kb * 32);
            float4 yb = *(const float4*)(px1 + kb * 32 + 4);
            half8 c = { (_Float16)ya.x, (_Float16)ya.y, (_Float16)ya.z, (_Float16)ya.w,
                        (_Float16)yb.x, (_Float16)yb.y, (_Float16)yb.z, (_Float16)yb.w };
            afr[1] = c;
        }
        // B-frags: ds_read_b128 from transposed strip
        half8 bfr[2];
        bfr[0] = *(const half8*)&Ts[ln][k8];
        bfr[1] = *(const half8*)&Ts[16 + ln][k8];
        #pragma unroll
        for (int mt = 0; mt < 2; ++mt)
            #pragma unroll
            for (int nt = 0; nt < 2; ++nt)
                acc[mt][nt] = __builtin_amdgcn_mfma_f32_16x16x32_f16(
                    afr[mt], bfr[nt], acc[mt][nt], 0, 0, 0);
    }

    // C/D: col = lane&15 (n), row = quad*4 + r (m)
    if (!isE) {
        float bv[2] = { b1[n0g + ln], b1[n0g + 16 + ln] };
        #pragma unroll
        for (int mt = 0; mt < 2; ++mt)
            #pragma unroll
            for (int nt = 0; nt < 2; ++nt) {
                int n = n0g + nt * 16 + ln;
                #pragma unroll
                for (int r = 0; r < 4; ++r) {
                    int m = m0 + mt * 16 + quad * 4 + r;
                    Pxs2[(size_t)m * H + n] = (_Float16)(acc[mt][nt][r] + bv[nt]);
                }
            }
    } else {
        #pragma unroll
        for (int mt = 0; mt < 2; ++mt)
            #pragma unroll
            for (int nt = 0; nt < 2; ++nt) {
                int n = n0g - H + nt * 16 + ln;
                #pragma unroll
                for (int r = 0; r < 4; ++r) {
                    int m = m0 + mt * 16 + quad * 4 + r;
                    Pxe[(size_t)m * H + n] = (_Float16)acc[mt][nt][r];
                }
            }
    }
}

// ---------------- Kernel 2: packed-fp16 gelu + MFMA W2 reduction -------------
// grid 1024: block = (b,i). 4 waves x 4 m-tiles = 256 j. Prefetched xe loads.
__global__ __launch_bounds__(256, 4) void span_mfma_kernel(
    const _Float16* __restrict__ Pxs2, const _Float16* __restrict__ Pxe,
    const _Float16* __restrict__ Bfrag2, const float* __restrict__ b2,
    float* __restrict__ out)
{
    __shared__ unsigned int xs2[H / 2];     // fp16 pairs
    const int bi = blockIdx.x;               // b*L + i
    const int b = bi >> 8;
    const int tid = threadIdx.x;
    const unsigned int* xrow = (const unsigned int*)(Pxs2 + (size_t)bi * H);
    for (int t = tid; t < H / 2; t += 256) xs2[t] = xrow[t];

    const int wave = tid >> 6;
    const int lane = tid & 63;
    const int n = lane & 15;
    const int quad = lane >> 4;
    const int j_base = wave * 64;

    const _Float16* xerow[4];
    #pragma unroll
    for (int t = 0; t < 4; ++t)
        xerow[t] = Pxe + (size_t)(b * L + j_base + t * 16 + n) * H + quad * 8;

    f32x4 acc[4] = {};
    __syncthreads();

    uint4 cur[4];
    #pragma unroll
    for (int t = 0; t < 4; ++t) cur[t] = *(const uint4*)(xerow[t]);

    #pragma unroll 2
    for (int kb = 0; kb < H / 32; ++kb) {
        const int k8 = kb * 32 + quad * 8;
        half8 bfrag = *(const half8*)(Bfrag2 + ((size_t)kb * 64 + lane) * 8);
        uint4 xsd = *(const uint4*)&xs2[k8 >> 1];
        h2 xsp[4] = { __builtin_bit_cast(h2, xsd.x), __builtin_bit_cast(h2, xsd.y),
                      __builtin_bit_cast(h2, xsd.z), __builtin_bit_cast(h2, xsd.w) };

        const int koff = (kb < H / 32 - 1) ? (kb + 1) * 32 : kb * 32;   // uniform
        uint4 nxt[4];
        #pragma unroll
        for (int t = 0; t < 4; ++t)
            nxt[t] = *(const uint4*)(xerow[t] - kb * 32 + koff - 32 + kb * 32 + 32);  // = xerow[t] + koff - quad*8 offset already in ptr

        #pragma unroll
        for (int t = 0; t < 4; ++t) {
            h2 xep[4] = { __builtin_bit_cast(h2, cur[t].x), __builtin_bit_cast(h2, cur[t].y),
                          __builtin_bit_cast(h2, cur[t].z), __builtin_bit_cast(h2, cur[t].w) };
            unsigned int pk[4];
            #pragma unroll
            for (int p = 0; p < 4; ++p) {
                h2 g = gelu_pk(xsp[p] + xep[p]);
                pk[p] = __builtin_bit_cast(unsigned int, g);
            }
            uint4 pk4 = {pk[0], pk[1], pk[2], pk[3]};
            half8 afrag = __builtin_bit_cast(half8, pk4);
            acc[t] = __builtin_amdgcn_mfma_f32_16x16x32_f16(afrag, bfrag, acc[t], 0, 0, 0);
            cur[t] = nxt[t];
        }
    }

    if (n < NL) {
        float b2v = b2[n];
        #pragma unroll
        for (int t = 0; t < 4; ++t)
            #pragma unroll
            for (int r = 0; r < 4; ++r) {
                int j = j_base + t * 16 + quad * 4 + r;
                out[((size_t)bi * L + j) * NL + n] = acc[t][r] + b2v;
            }
    }
}

// ---------------- Launch ------------------------------------------------------
extern "C" void kernel_launch(void* const* d_in, const int* in_sizes, int n_in,
                              void* d_out, int out_size, void* d_ws, size_t ws_size,
                              hipStream_t stream)
{
    (void)in_sizes; (void)n_in; (void)out_size; (void)ws_size;
    const float* X  = (const float*)d_in[0];
    const float* W1 = (const float*)d_in[1];
    const float* b1 = (const float*)d_in[2];
    const float* W2 = (const float*)d_in[3];
    const float* b2 = (const float*)d_in[4];
    float* out = (float*)d_out;

    char* ws = (char*)d_ws;
    _Float16* Pxs2   = (_Float16*)ws;                          // 1.5 MB
    _Float16* Pxe    = Pxs2 + (size_t)NB * L * H;              // 1.5 MB
    _Float16* Bfrag2 = Pxe + (size_t)NB * L * H;               // 24 KB

    fused_gemm<<<dim3(48, 9), 256, 0, stream>>>(X, W1, b1, W2, Pxs2, Pxe, Bfrag2);
    span_mfma_kernel<<<NB * L, 256, 0, stream>>>(Pxs2, Pxe, Bfrag2, b2, out);
}

// Round 7
// 134.805 us; speedup vs baseline: 1.0790x; 1.0790x over previous
//
#include <hip/hip_runtime.h>
#include <math.h>

#define H 768
#define L 256
#define NB 4
#define NL 13

typedef _Float16 h2 __attribute__((ext_vector_type(2)));
typedef _Float16 half8 __attribute__((ext_vector_type(8)));
typedef float f32x4 __attribute__((ext_vector_type(4)));

// Packed-fp16 GELU: erf(x/sqrt2) ~= xc*P(v), v = (xc*xc)/8, xc = clamp(x,+-3.75).
__device__ inline h2 gelu_pk(h2 x) {
    const _Float16 kC = (_Float16)3.75f;
    h2 hi = {kC, kC}, lo = {(_Float16)-3.75f, (_Float16)-3.75f};
    h2 xc = __builtin_elementwise_min(__builtin_elementwise_max(x, lo), hi);
    h2 u = xc * xc;
    const _Float16 kE = (_Float16)0.125f;
    h2 ve = {kE, kE};
    h2 v = u * ve;
    const _Float16 d4v = (_Float16)0.0832840f,  d3v = (_Float16)-0.4335206f;
    const _Float16 d2v = (_Float16)0.8960128f,  d1v = (_Float16)-0.9876456f;
    const _Float16 d0v = (_Float16)0.7946463f;
    h2 d4 = {d4v, d4v}, d3 = {d3v, d3v}, d2 = {d2v, d2v}, d1 = {d1v, d1v}, d0 = {d0v, d0v};
    h2 p = v * (v * (v * (v * d4 + d3) + d2) + d1) + d0;   // v_pk_fma_f16 chain
    h2 t = xc * p;
    const _Float16 kH = (_Float16)0.5f;
    h2 halfv = {kH, kH};
    h2 hx = x * halfv;
    return hx * t + hx;
}

// ---------------- Prep: pack everything into MFMA fragment order -------------
// blk <  64          : Afrag[mt][kb][lane][8] = fp16 X[(mt*16+ln)*H + kb*32+q*8+u]
// 64 <= blk < 1216   : Bfrag1[ntg][kb][lane][8] = fp16 W1view[kb*32+q*8+u][ntg*16+ln]
// blk >= 1216 (16)   : Bfrag2[kb][lane][8] = fp16 W2[k][n] (n=ln<13 else 0)
__global__ __launch_bounds__(256) void prep_kernel(
    const float* __restrict__ X, const float* __restrict__ W1,
    const float* __restrict__ W2,
    _Float16* __restrict__ Afrag, _Float16* __restrict__ Bfrag1,
    _Float16* __restrict__ Bfrag2)
{
    __shared__ __align__(16) unsigned char smem[16 * 784 * 2];
    const int blk = blockIdx.x;
    const int tid = threadIdx.x;

    if (blk < 64) {
        _Float16* T = (_Float16*)smem;
        const int mt = blk;
        const int row = tid >> 4, colg = tid & 15;
        #pragma unroll
        for (int cc = 0; cc < 12; ++cc) {
            int c4 = (colg + cc * 16) * 4;
            float4 f = *(const float4*)&X[(size_t)(mt * 16 + row) * H + c4];
            _Float16* d = T + row * 784 + c4;
            d[0] = (_Float16)f.x; d[1] = (_Float16)f.y;
            d[2] = (_Float16)f.z; d[3] = (_Float16)f.w;
        }
        __syncthreads();
        #pragma unroll
        for (int rr = 0; rr < 12; ++rr) {
            int kb = rr * 2 + (tid >> 7);
            int sub = tid & 127;
            int lane = sub >> 1, u4 = (sub & 1) * 4;
            int ln = lane & 15, q = lane >> 4;
            const _Float16* s = T + ln * 784 + kb * 32 + q * 8 + u4;
            ushort4 o = { *(const unsigned short*)&s[0], *(const unsigned short*)&s[1],
                          *(const unsigned short*)&s[2], *(const unsigned short*)&s[3] };
            *(ushort4*)&Afrag[(((size_t)mt * 24 + kb) * 64 + lane) * 8 + u4] = o;
        }
    } else if (blk < 64 + 1152) {
        _Float16* T = (_Float16*)smem;       // tile[32][36], [k][n]
        const int t2 = blk - 64;
        const int kb = t2 % 24, ng = t2 / 24;
        const int n0p = ng * 32;
        const float* Wb = W1 + ((n0p >= H) ? (size_t)H * H : 0);
        const int c0 = n0p - ((n0p >= H) ? H : 0);
        const int row = tid >> 3, c4 = (tid & 7) * 4;
        float4 f = *(const float4*)&Wb[(size_t)(kb * 32 + row) * H + c0 + c4];
        _Float16* d = T + row * 36 + c4;
        d[0] = (_Float16)f.x; d[1] = (_Float16)f.y;
        d[2] = (_Float16)f.z; d[3] = (_Float16)f.w;
        __syncthreads();
        int u4 = (tid & 1) * 4;
        int lane = (tid >> 1) & 63;
        int nts = tid >> 7;
        int ln = lane & 15, q = lane >> 4;
        ushort4 o;
        unsigned short* os = (unsigned short*)&o;
        #pragma unroll
        for (int i = 0; i < 4; ++i)
            os[i] = *(const unsigned short*)&T[(q * 8 + u4 + i) * 36 + nts * 16 + ln];
        int ntg = (n0p >> 4) + nts;
        *(ushort4*)&Bfrag1[(((size_t)ntg * 24 + kb) * 64 + lane) * 8 + u4] = o;
    } else {
        int base = (blk - 64 - 1152) * 768 + tid;
        #pragma unroll
        for (int r = 0; r < 3; ++r) {
            int idx = base + r * 256;
            int u = idx & 7;
            int lane = (idx >> 3) & 63;
            int kb = idx >> 9;
            int k = kb * 32 + ((lane >> 4) << 3) + u;
            int n = lane & 15;
            float v = (n < NL) ? W2[(size_t)k * NL + n] : 0.f;
            Bfrag2[idx] = (_Float16)v;
        }
    }
}

// ---------------- Stage 1: MFMA GEMM, fragment-direct, no LDS ----------------
__global__ __launch_bounds__(256) void gemm_mfma(
    const _Float16* __restrict__ Afrag, const _Float16* __restrict__ Bfrag1,
    const float* __restrict__ b1, _Float16* __restrict__ Pxs2,
    _Float16* __restrict__ Pxe)
{
    const int tid = threadIdx.x;
    const int w = tid >> 6, lane = tid & 63;
    const int ln = lane & 15, quad = lane >> 4;
    const int m0 = blockIdx.x * 64 + (w & 1) * 32;
    const int n0g = blockIdx.y * 64 + (w >> 1) * 32;
    const int mt0 = m0 >> 4, ntg0 = n0g >> 4;

    const half8* pa0 = (const half8*)(Afrag + (((size_t)mt0 * 24) * 64 + lane) * 8);
    const half8* pa1 = (const half8*)(Afrag + ((((size_t)mt0 + 1) * 24) * 64 + lane) * 8);
    const half8* pb0 = (const half8*)(Bfrag1 + (((size_t)ntg0 * 24) * 64 + lane) * 8);
    const half8* pb1 = (const half8*)(Bfrag1 + ((((size_t)ntg0 + 1) * 24) * 64 + lane) * 8);

    f32x4 acc[2][2] = {};
    #pragma unroll 4
    for (int kb = 0; kb < 24; ++kb) {
        half8 a0 = pa0[kb * 64];
        half8 a1 = pa1[kb * 64];
        half8 b0 = pb0[kb * 64];
        half8 b1v = pb1[kb * 64];
        acc[0][0] = __builtin_amdgcn_mfma_f32_16x16x32_f16(a0, b0, acc[0][0], 0, 0, 0);
        acc[0][1] = __builtin_amdgcn_mfma_f32_16x16x32_f16(a0, b1v, acc[0][1], 0, 0, 0);
        acc[1][0] = __builtin_amdgcn_mfma_f32_16x16x32_f16(a1, b0, acc[1][0], 0, 0, 0);
        acc[1][1] = __builtin_amdgcn_mfma_f32_16x16x32_f16(a1, b1v, acc[1][1], 0, 0, 0);
    }

    if (n0g < H) {
        float bv[2] = { b1[n0g + ln], b1[n0g + 16 + ln] };
        #pragma unroll
        for (int mt = 0; mt < 2; ++mt)
            #pragma unroll
            for (int nt = 0; nt < 2; ++nt) {
                int n = n0g + nt * 16 + ln;
                #pragma unroll
                for (int r = 0; r < 4; ++r) {
                    int m = m0 + mt * 16 + quad * 4 + r;
                    Pxs2[(size_t)m * H + n] = (_Float16)(acc[mt][nt][r] + bv[nt]);
                }
            }
    } else {
        #pragma unroll
        for (int mt = 0; mt < 2; ++mt)
            #pragma unroll
            for (int nt = 0; nt < 2; ++nt) {
                int n = n0g - H + nt * 16 + ln;
                #pragma unroll
                for (int r = 0; r < 4; ++r) {
                    int m = m0 + mt * 16 + quad * 4 + r;
                    Pxe[(size_t)m * H + n] = (_Float16)acc[mt][nt][r];
                }
            }
    }
}

// ---------------- Stage 2: packed-fp16 gelu + MFMA W2 reduction --------------
// grid 2048: block = (b,i,jhalf). 4 waves x 2 m-tiles = 128 j per block.
// kb+1 xe prefetch hides L2 latency; occupancy config identical to R5.
__global__ __launch_bounds__(256, 6) void span_mfma_kernel(
    const _Float16* __restrict__ Pxs2, const _Float16* __restrict__ Pxe,
    const _Float16* __restrict__ Bfrag2, const float* __restrict__ b2,
    float* __restrict__ out)
{
    __shared__ unsigned int xs2[H / 2];     // fp16 pairs
    const int bi = blockIdx.x >> 1;          // b*L + i
    const int jh = blockIdx.x & 1;
    const int b = bi >> 8;
    const int tid = threadIdx.x;
    const unsigned int* xrow = (const unsigned int*)(Pxs2 + (size_t)bi * H);
    for (int t = tid; t < H / 2; t += 256) xs2[t] = xrow[t];

    const int wave = tid >> 6;
    const int lane = tid & 63;
    const int n = lane & 15;
    const int quad = lane >> 4;
    const int j_base = jh * 128 + wave * 32;

    const _Float16* xerow[2];
    #pragma unroll
    for (int t = 0; t < 2; ++t)
        xerow[t] = Pxe + (size_t)(b * L + j_base + t * 16 + n) * H + quad * 8;

    f32x4 acc[2] = {};
    __syncthreads();

    uint4 cur[2] = { *(const uint4*)xerow[0], *(const uint4*)xerow[1] };

    for (int kb = 0; kb < H / 32; ++kb) {
        half8 bfrag = *(const half8*)(Bfrag2 + ((size_t)kb * 64 + lane) * 8);
        uint4 xsd = *(const uint4*)&xs2[(kb * 32 + quad * 8) >> 1];
        h2 xsp[4] = { __builtin_bit_cast(h2, xsd.x), __builtin_bit_cast(h2, xsd.y),
                      __builtin_bit_cast(h2, xsd.z), __builtin_bit_cast(h2, xsd.w) };

        const int knext = ((kb < H / 32 - 1) ? (kb + 1) : kb) * 32;   // wave-uniform
        uint4 nxt[2] = { *(const uint4*)(xerow[0] + knext),
                         *(const uint4*)(xerow[1] + knext) };

        #pragma unroll
        for (int t = 0; t < 2; ++t) {
            h2 xep[4] = { __builtin_bit_cast(h2, cur[t].x), __builtin_bit_cast(h2, cur[t].y),
                          __builtin_bit_cast(h2, cur[t].z), __builtin_bit_cast(h2, cur[t].w) };
            unsigned int pk[4];
            #pragma unroll
            for (int p = 0; p < 4; ++p) {
                h2 g = gelu_pk(xsp[p] + xep[p]);
                pk[p] = __builtin_bit_cast(unsigned int, g);
            }
            uint4 pk4 = {pk[0], pk[1], pk[2], pk[3]};
            half8 afrag = __builtin_bit_cast(half8, pk4);
            acc[t] = __builtin_amdgcn_mfma_f32_16x16x32_f16(afrag, bfrag, acc[t], 0, 0, 0);
            cur[t] = nxt[t];
        }
    }

    if (n < NL) {
        float b2v = b2[n];
        #pragma unroll
        for (int t = 0; t < 2; ++t)
            #pragma unroll
            for (int r = 0; r < 4; ++r) {
                int j = j_base + t * 16 + quad * 4 + r;
                out[((size_t)bi * L + j) * NL + n] = acc[t][r] + b2v;
            }
    }
}

// ---------------- Launch ------------------------------------------------------
extern "C" void kernel_launch(void* const* d_in, const int* in_sizes, int n_in,
                              void* d_out, int out_size, void* d_ws, size_t ws_size,
                              hipStream_t stream)
{
    (void)in_sizes; (void)n_in; (void)out_size; (void)ws_size;
    const float* X  = (const float*)d_in[0];
    const float* W1 = (const float*)d_in[1];
    const float* b1 = (const float*)d_in[2];
    const float* W2 = (const float*)d_in[3];
    const float* b2 = (const float*)d_in[4];
    float* out = (float*)d_out;

    char* ws = (char*)d_ws;
    _Float16* Pxs2   = (_Float16*)ws;                          // 1.5 MB
    _Float16* Pxe    = Pxs2 + (size_t)NB * L * H;              // 1.5 MB
    _Float16* Afrag  = Pxe + (size_t)NB * L * H;               // 1.5 MB
    _Float16* Bfrag1 = Afrag + (size_t)NB * L * H;             // 2.25 MB
    _Float16* Bfrag2 = Bfrag1 + (size_t)2 * H * H;             // 24 KB

    prep_kernel<<<64 + 1152 + 16, 256, 0, stream>>>(X, W1, W2, Afrag, Bfrag1, Bfrag2);
    gemm_mfma<<<dim3(16, 24), 256, 0, stream>>>(Afrag, Bfrag1, b1, Pxs2, Pxe);
    span_mfma_kernel<<<NB * L * 2, 256, 0, stream>>>(Pxs2, Pxe, Bfrag2, b2, out);
}

// Round 8
// 124.588 us; speedup vs baseline: 1.1675x; 1.0820x over previous
//
#include <hip/hip_runtime.h>
#include <math.h>

#define H 768
#define L 256
#define NB 4
#define NL 13

typedef _Float16 h2 __attribute__((ext_vector_type(2)));
typedef _Float16 half8 __attribute__((ext_vector_type(8)));
typedef float f32x4 __attribute__((ext_vector_type(4)));

// Packed-fp16 GELU: erf(x/sqrt2) ~= xc*P(v), v = (xc*xc)/8, xc = clamp(x,+-3.75).
__device__ inline h2 gelu_pk(h2 x) {
    const _Float16 kC = (_Float16)3.75f;
    h2 hi = {kC, kC}, lo = {(_Float16)-3.75f, (_Float16)-3.75f};
    h2 xc = __builtin_elementwise_min(__builtin_elementwise_max(x, lo), hi);
    h2 u = xc * xc;
    const _Float16 kE = (_Float16)0.125f;
    h2 ve = {kE, kE};
    h2 v = u * ve;
    const _Float16 d4v = (_Float16)0.0832840f,  d3v = (_Float16)-0.4335206f;
    const _Float16 d2v = (_Float16)0.8960128f,  d1v = (_Float16)-0.9876456f;
    const _Float16 d0v = (_Float16)0.7946463f;
    h2 d4 = {d4v, d4v}, d3 = {d3v, d3v}, d2 = {d2v, d2v}, d1 = {d1v, d1v}, d0 = {d0v, d0v};
    h2 p = v * (v * (v * (v * d4 + d3) + d2) + d1) + d0;   // v_pk_fma_f16 chain
    h2 t = xc * p;
    const _Float16 kH = (_Float16)0.5f;
    h2 halfv = {kH, kH};
    h2 hx = x * halfv;
    return hx * t + hx;
}

// ---------------- Prep v2: direct global->global fragment packing ------------
// No LDS, no barriers, coalesced 16B stores.
// blocks [0,384)   : Afrag[(mt*24+kb)*64+lane][8] = fp16 X[mt*16+(lane&15)][kb*32+(lane>>4)*8 + u]
// blocks [384,960) : Bfrag1[(ntg*24+kb)*64+lane][8] = fp16 W1view[kb*32+(lane>>4)*8+u][ntg*16+(lane&15)]
// blocks [960,976) : Bfrag2[kb][lane][8] = fp16 W2[k][n] (n=lane&15 <13 else 0)
__global__ __launch_bounds__(256) void prep_kernel(
    const float* __restrict__ X, const float* __restrict__ W1,
    const float* __restrict__ W2,
    _Float16* __restrict__ Afrag, _Float16* __restrict__ Bfrag1,
    _Float16* __restrict__ Bfrag2)
{
    const int blk = blockIdx.x;
    const int tid = threadIdx.x;

    if (blk < 384) {
        int t = blk * 256 + tid;                 // [0, 98304)
        int lane = t & 63;
        int g = t >> 6;                          // [0, 1536)
        int kb = g % 24, mt = g / 24;
        int m = mt * 16 + (lane & 15);
        int k0 = kb * 32 + (lane >> 4) * 8;
        const float* px = X + (size_t)m * H + k0;
        float4 a = *(const float4*)px;
        float4 b = *(const float4*)(px + 4);
        half8 o = { (_Float16)a.x, (_Float16)a.y, (_Float16)a.z, (_Float16)a.w,
                    (_Float16)b.x, (_Float16)b.y, (_Float16)b.z, (_Float16)b.w };
        *(half8*)(Afrag + (size_t)t * 8) = o;
    } else if (blk < 960) {
        int t = (blk - 384) * 256 + tid;         // [0, 147456)
        int lane = t & 63;
        int g = t >> 6;                          // [0, 2304)
        int kb = g % 24, ntg = g / 24;           // ntg in [0,96)
        int np = ntg * 16 + (lane & 15);         // n' in [0,1536)
        int k0 = kb * 32 + (lane >> 4) * 8;
        const float* Wb = W1 + ((np >= H) ? (size_t)H * H : 0);
        int c = np - ((np >= H) ? H : 0);
        half8 o;
        #pragma unroll
        for (int u = 0; u < 8; ++u)
            o[u] = (_Float16)Wb[(size_t)(k0 + u) * H + c];
        *(half8*)(Bfrag1 + (size_t)t * 8) = o;
    } else {
        int base = (blk - 960) * 768 + tid;
        #pragma unroll
        for (int r = 0; r < 3; ++r) {
            int idx = base + r * 256;            // < 12288
            int u = idx & 7;
            int lane = (idx >> 3) & 63;
            int kb = idx >> 9;
            int k = kb * 32 + ((lane >> 4) << 3) + u;
            int n = lane & 15;
            float v = (n < NL) ? W2[(size_t)k * NL + n] : 0.f;
            Bfrag2[idx] = (_Float16)v;
        }
    }
}

// ---------------- Stage 1: MFMA GEMM, fragment-direct, no LDS ----------------
__global__ __launch_bounds__(256) void gemm_mfma(
    const _Float16* __restrict__ Afrag, const _Float16* __restrict__ Bfrag1,
    const float* __restrict__ b1, _Float16* __restrict__ Pxs2,
    _Float16* __restrict__ Pxe)
{
    const int tid = threadIdx.x;
    const int w = tid >> 6, lane = tid & 63;
    const int ln = lane & 15, quad = lane >> 4;
    const int m0 = blockIdx.x * 64 + (w & 1) * 32;
    const int n0g = blockIdx.y * 64 + (w >> 1) * 32;
    const int mt0 = m0 >> 4, ntg0 = n0g >> 4;

    const half8* pa0 = (const half8*)(Afrag + (((size_t)mt0 * 24) * 64 + lane) * 8);
    const half8* pa1 = (const half8*)(Afrag + ((((size_t)mt0 + 1) * 24) * 64 + lane) * 8);
    const half8* pb0 = (const half8*)(Bfrag1 + (((size_t)ntg0 * 24) * 64 + lane) * 8);
    const half8* pb1 = (const half8*)(Bfrag1 + ((((size_t)ntg0 + 1) * 24) * 64 + lane) * 8);

    f32x4 acc[2][2] = {};
    #pragma unroll 4
    for (int kb = 0; kb < 24; ++kb) {
        half8 a0 = pa0[kb * 64];
        half8 a1 = pa1[kb * 64];
        half8 b0 = pb0[kb * 64];
        half8 b1v = pb1[kb * 64];
        acc[0][0] = __builtin_amdgcn_mfma_f32_16x16x32_f16(a0, b0, acc[0][0], 0, 0, 0);
        acc[0][1] = __builtin_amdgcn_mfma_f32_16x16x32_f16(a0, b1v, acc[0][1], 0, 0, 0);
        acc[1][0] = __builtin_amdgcn_mfma_f32_16x16x32_f16(a1, b0, acc[1][0], 0, 0, 0);
        acc[1][1] = __builtin_amdgcn_mfma_f32_16x16x32_f16(a1, b1v, acc[1][1], 0, 0, 0);
    }

    if (n0g < H) {
        float bv[2] = { b1[n0g + ln], b1[n0g + 16 + ln] };
        #pragma unroll
        for (int mt = 0; mt < 2; ++mt)
            #pragma unroll
            for (int nt = 0; nt < 2; ++nt) {
                int n = n0g + nt * 16 + ln;
                #pragma unroll
                for (int r = 0; r < 4; ++r) {
                    int m = m0 + mt * 16 + quad * 4 + r;
                    Pxs2[(size_t)m * H + n] = (_Float16)(acc[mt][nt][r] + bv[nt]);
                }
            }
    } else {
        #pragma unroll
        for (int mt = 0; mt < 2; ++mt)
            #pragma unroll
            for (int nt = 0; nt < 2; ++nt) {
                int n = n0g - H + nt * 16 + ln;
                #pragma unroll
                for (int r = 0; r < 4; ++r) {
                    int m = m0 + mt * 16 + quad * 4 + r;
                    Pxe[(size_t)m * H + n] = (_Float16)acc[mt][nt][r];
                }
            }
    }
}

// ---------------- Stage 2: span — 2 i-rows per block, shared xe loads --------
// grid 2048: block = (ipair, jquarter). Each wave: 16 j (one m-tile) x 2 i.
// Every xe 16B load feeds 2 gelu+MFMA streams. Bfrag2 (24 KB) is L1-resident.
__global__ __launch_bounds__(256, 4) void span_mfma_kernel(
    const _Float16* __restrict__ Pxs2, const _Float16* __restrict__ Pxe,
    const _Float16* __restrict__ Bfrag2, const float* __restrict__ b2,
    float* __restrict__ out)
{
    __shared__ unsigned int xsf[2 * H / 2];   // two i-rows of fp16 pairs (3 KB)
    const int ip = blockIdx.x >> 2;           // 0..511
    const int jq = blockIdx.x & 3;
    const int bi0 = ip * 2;                   // b*L + i (pair start; same b: L even)
    const int b = bi0 >> 8;
    const int tid = threadIdx.x;

    // rows bi0, bi0+1 are contiguous in Pxs2: copy 768 uints flat
    const unsigned int* xsrc = (const unsigned int*)(Pxs2 + (size_t)bi0 * H);
    for (int t = tid; t < H; t += 256) xsf[t] = xsrc[t];

    const int wave = tid >> 6;
    const int lane = tid & 63;
    const int n = lane & 15;
    const int quad = lane >> 4;
    const int j_load = jq * 64 + wave * 16 + n;       // A-frag row m = lane&15

    const _Float16* xerow = Pxe + (size_t)(b * L + j_load) * H + quad * 8;
    const half8* bptr = (const half8*)(Bfrag2 + (size_t)lane * 8);

    f32x4 acc[2] = {};
    __syncthreads();

    for (int kb = 0; kb < H / 32; ++kb) {
        half8 bfrag = bptr[kb * 64];
        uint4 xev = *(const uint4*)(xerow + kb * 32);
        h2 xep[4] = { __builtin_bit_cast(h2, xev.x), __builtin_bit_cast(h2, xev.y),
                      __builtin_bit_cast(h2, xev.z), __builtin_bit_cast(h2, xev.w) };
        const int xo = kb * 16 + quad * 4;            // uint index of this lane's 8 fp16

        #pragma unroll
        for (int i01 = 0; i01 < 2; ++i01) {
            uint4 xsd = *(const uint4*)&xsf[i01 * (H / 2) + xo];
            h2 xsp[4] = { __builtin_bit_cast(h2, xsd.x), __builtin_bit_cast(h2, xsd.y),
                          __builtin_bit_cast(h2, xsd.z), __builtin_bit_cast(h2, xsd.w) };
            unsigned int pk[4];
            #pragma unroll
            for (int p = 0; p < 4; ++p) {
                h2 g = gelu_pk(xsp[p] + xep[p]);
                pk[p] = __builtin_bit_cast(unsigned int, g);
            }
            uint4 pk4 = {pk[0], pk[1], pk[2], pk[3]};
            half8 afrag = __builtin_bit_cast(half8, pk4);
            acc[i01] = __builtin_amdgcn_mfma_f32_16x16x32_f16(afrag, bfrag, acc[i01], 0, 0, 0);
        }
    }

    // C/D: col = lane&15 = label n, row = quad*4 + r = j-offset in the m-tile
    if (n < NL) {
        float b2v = b2[n];
        #pragma unroll
        for (int i01 = 0; i01 < 2; ++i01)
            #pragma unroll
            for (int r = 0; r < 4; ++r) {
                int j = jq * 64 + wave * 16 + quad * 4 + r;
                out[((size_t)(bi0 + i01) * L + j) * NL + n] = acc[i01][r] + b2v;
            }
    }
}

// ---------------- Launch ------------------------------------------------------
extern "C" void kernel_launch(void* const* d_in, const int* in_sizes, int n_in,
                              void* d_out, int out_size, void* d_ws, size_t ws_size,
                              hipStream_t stream)
{
    (void)in_sizes; (void)n_in; (void)out_size; (void)ws_size;
    const float* X  = (const float*)d_in[0];
    const float* W1 = (const float*)d_in[1];
    const float* b1 = (const float*)d_in[2];
    const float* W2 = (const float*)d_in[3];
    const float* b2 = (const float*)d_in[4];
    float* out = (float*)d_out;

    char* ws = (char*)d_ws;
    _Float16* Pxs2   = (_Float16*)ws;                          // 1.5 MB
    _Float16* Pxe    = Pxs2 + (size_t)NB * L * H;              // 1.5 MB
    _Float16* Afrag  = Pxe + (size_t)NB * L * H;               // 1.5 MB
    _Float16* Bfrag1 = Afrag + (size_t)NB * L * H;             // 2.25 MB
    _Float16* Bfrag2 = Bfrag1 + (size_t)2 * H * H;             // 24 KB

    prep_kernel<<<976, 256, 0, stream>>>(X, W1, W2, Afrag, Bfrag1, Bfrag2);
    gemm_mfma<<<dim3(16, 24), 256, 0, stream>>>(Afrag, Bfrag1, b1, Pxs2, Pxe);
    span_mfma_kernel<<<NB * L * 2, 256, 0, stream>>>(Pxs2, Pxe, Bfrag2, b2, out);
}